// Round 4
// baseline (186.245 us; speedup 1.0000x reference)
//
#include <hip/hip_runtime.h>
#include <hip/hip_bf16.h>
#include <stdint.h>

// bf16 MFMA pipeline, v9. B=2, L=2048, D=1024, H=16, dh=64.
// a2 = softmax(s_prev) is a column permutation of a1 -> o = lam * A1 @ (v - roll(v,-1)).
// v9: attention processes TWO j-tiles per barrier interval (4 LDS buffers, pair
// double-buffer). Prefetch next pair at iteration top into the pair consumed
// last iteration; vmcnt(0)+s_barrier once per pair (loads get a full 2-tile
// compute of cover). 2x independent dep-chains per wave -> MFMA/VALU overlap;
// barrier count halved. Cross-jw reduction aliased onto staging LDS.

typedef __attribute__((ext_vector_type(8))) short s16x8;
typedef __attribute__((ext_vector_type(4))) short s16x4;
typedef __attribute__((ext_vector_type(4))) float f32x4;
typedef __attribute__((ext_vector_type(4))) unsigned int u32x4;

__device__ __forceinline__ float bf2f(unsigned short u) {
    union { unsigned int i; float f; } x; x.i = ((unsigned int)u) << 16; return x.f;
}
__device__ __forceinline__ unsigned short f2bf(float f) {
    union { float f; unsigned int i; } x; x.f = f;
    unsigned int r = x.i + 0x7FFFu + ((x.i >> 16) & 1u);   // RNE
    return (unsigned short)(r >> 16);
}

// async global->LDS, 16B/lane; LDS dest = wave-uniform base + lane*16
__device__ __forceinline__ void gload16(const void* g, void* l) {
    auto gp = reinterpret_cast<const __attribute__((address_space(1))) unsigned int*>(
        reinterpret_cast<uintptr_t>(g));
    auto lp = reinterpret_cast<__attribute__((address_space(3))) unsigned int*>(
        reinterpret_cast<uintptr_t>(l));
    __builtin_amdgcn_global_load_lds(gp, lp, 16, 0, 0);
}

__global__ __launch_bounds__(256) void cvt_all(
    const float* __restrict__ x, const float* __restrict__ wq,
    const float* __restrict__ wo,
    unsigned short* __restrict__ xb, unsigned short* __restrict__ wqb,
    unsigned short* __restrict__ wob)
{
    int i4 = blockIdx.x * 256 + threadIdx.x;   // float4 index
    const float* src; unsigned short* dst; int off;
    if (i4 < 1048576)            { src = x;  dst = xb;  off = i4; }
    else if (i4 < 1048576 + 786432) { src = wq; dst = wqb; off = i4 - 1048576; }
    else                         { src = wo; dst = wob; off = i4 - 1835008; }
    float4 v = ((const float4*)src)[off];
    ushort4 u;
    u.x = f2bf(v.x); u.y = f2bf(v.y); u.z = f2bf(v.z); u.w = f2bf(v.w);
    ((ushort4*)dst)[off] = u;
}

// vdt[b][h][dh][pos] = v[b, j(pos), h, dh] - v[b, (j(pos)+1)%L, h, dh], transposed
// via LDS. Within each 32-j block, pos(j) = ((j>>2)&3)*8 + ((j>>4)&1)*4 + (j&3),
// i.e. position k = quad*8 + t*4 + rg holds j = t*16 + quad*4 + rg — the exact
// k-layout of the 16x16x32 MFMA A/B operand vs the 16x16 C-layout of S^T.
__global__ __launch_bounds__(256) void vd_transpose(
    const unsigned short* __restrict__ qkvb, unsigned short* __restrict__ vdt)
{
    __shared__ unsigned short T[64][72];
    const int tid = threadIdx.x;
    const int j0 = blockIdx.x * 64;
    const int bh = blockIdx.y, b = bh >> 4, h = bh & 15;
    const unsigned short* vb = qkvb + (size_t)b * 2048 * 3072 + 2048 + h * 64;

    int r = tid >> 2, cq = tid & 3;
    int rp = (r & 35) | ((r & 12) << 1) | ((r & 16) >> 2);   // permuted column
    int j = j0 + r, jn = (j + 1) & 2047;
    const unsigned short* p0 = vb + (size_t)j  * 3072 + cq * 16;
    const unsigned short* p1 = vb + (size_t)jn * 3072 + cq * 16;
    s16x8 a0 = *(const s16x8*)p0, a1 = *(const s16x8*)(p0 + 8);
    s16x8 b0 = *(const s16x8*)p1, b1 = *(const s16x8*)(p1 + 8);
#pragma unroll
    for (int u = 0; u < 8; ++u)
        T[cq * 16 + u][rp] = f2bf(bf2f((unsigned short)a0[u]) - bf2f((unsigned short)b0[u]));
#pragma unroll
    for (int u = 0; u < 8; ++u)
        T[cq * 16 + 8 + u][rp] = f2bf(bf2f((unsigned short)a1[u]) - bf2f((unsigned short)b1[u]));
    __syncthreads();

    int row = tid >> 2, sc = tid & 3;
    s16x8 o0 = *(const s16x8*)&T[row][sc * 16];
    s16x8 o1 = *(const s16x8*)&T[row][sc * 16 + 8];
    unsigned short* dst = vdt + ((size_t)bh * 64 + row) * 2048 + j0 + sc * 16;
    *(s16x8*)dst = o0;
    *(s16x8*)(dst + 8) = o1;
}

// C[m,n] = sum_k A[m,k]*Bm[n,k] + bias[n]; cols < nscale additionally *= smul.
template <int OUT_BF16, int BN>
__global__ __launch_bounds__(256) void gemm_nt_mfma(
    const unsigned short* __restrict__ A,
    const unsigned short* __restrict__ Bm,
    const float* __restrict__ bias,
    void* __restrict__ C,
    int M, int N, int K, int nscale, float smul)
{
    constexpr int NT = BN / 32;
    __shared__ unsigned short As[2][128][32];
    __shared__ unsigned short Bs[2][BN][32];

    const int tid = threadIdx.x;
    const int wave = tid >> 6, lane = tid & 63;
    const int quad = lane >> 4, ln = lane & 15;
    const int wm = (wave >> 1) * 64, wn = (wave & 1) * (NT * 16);
    const int m0 = blockIdx.y * 128, n0 = blockIdx.x * BN;
    const int rA = wave * 16 + (lane >> 2);
    const int gsl = lane & 3;

    f32x4 acc[4][NT];
#pragma unroll
    for (int mt = 0; mt < 4; ++mt)
#pragma unroll
        for (int nt = 0; nt < NT; ++nt) acc[mt][nt] = f32x4{0.f, 0.f, 0.f, 0.f};

    auto stage = [&](int p, int k0) {
#pragma unroll
        for (int q = 0; q < 2; ++q) {
            int row = q * 64 + rA;
            int kg = gsl ^ ((row >> 1) & 3);
            gload16(A + (size_t)(m0 + row) * K + k0 + kg * 8,
                    &As[p][q * 64 + wave * 16][0]);
            if (q * 64 < BN)
                gload16(Bm + (size_t)(n0 + row) * K + k0 + kg * 8,
                        &Bs[p][q * 64 + wave * 16][0]);
        }
    };

    stage(0, 0);
    __syncthreads();
    int p = 0;
    for (int k0 = 0; k0 < K; k0 += 32) {
        if (k0 + 32 < K) stage(p ^ 1, k0 + 32);
        s16x8 af[4], bfr[NT];
#pragma unroll
        for (int mt = 0; mt < 4; ++mt) {
            int rr = wm + mt * 16 + ln;
            af[mt] = *(const s16x8*)&As[p][rr][((quad ^ ((rr >> 1) & 3)) & 3) * 8];
        }
#pragma unroll
        for (int nt = 0; nt < NT; ++nt) {
            int rr = wn + nt * 16 + ln;
            bfr[nt] = *(const s16x8*)&Bs[p][rr][((quad ^ ((rr >> 1) & 3)) & 3) * 8];
        }
#pragma unroll
        for (int mt = 0; mt < 4; ++mt)
#pragma unroll
            for (int nt = 0; nt < NT; ++nt)
                acc[mt][nt] = __builtin_amdgcn_mfma_f32_16x16x32_bf16(
                    af[mt], bfr[nt], acc[mt][nt], 0, 0, 0);
        __syncthreads();
        p ^= 1;
    }

    float bb[NT];
#pragma unroll
    for (int nt = 0; nt < NT; ++nt) bb[nt] = bias[n0 + wn + nt * 16 + ln];
#pragma unroll
    for (int mt = 0; mt < 4; ++mt)
#pragma unroll
        for (int nt = 0; nt < NT; ++nt) {
            int col = n0 + wn + nt * 16 + ln;
            float sc = (col < nscale) ? smul : 1.f;
#pragma unroll
            for (int rg = 0; rg < 4; ++rg) {
                int row = m0 + wm + mt * 16 + quad * 4 + rg;
                float v = (acc[mt][nt][rg] + bb[nt]) * sc;
                if (OUT_BF16)
                    ((unsigned short*)C)[(size_t)row * N + col] = f2bf(v);
                else
                    ((float*)C)[(size_t)row * N + col] = v;
            }
        }
}

// Differential attention, v9: 8 waves (512 thr). wave = jw*4+qw.
// qw owns 32 q-rows; jw in {0,1} owns a 32-row j-half of each 64-row K/V chunk.
// 4-buffer pair pipeline: each iteration computes tiles 2i,2i+1 and prefetches
// tiles 2i+2,2i+3 into the pair consumed in iteration i-1. One vmcnt(0)+barrier
// per pair. Cross-jw Ot/lacc reduction aliased onto staging LDS after the loop.
__global__ __launch_bounds__(512) void diff_attn_v9(
    const unsigned short* __restrict__ qkv,   // [B*L][3072] bf16 (Q pre-scaled by log2e/32)
    const unsigned short* __restrict__ vdt,   // [B*H][64][2048] bf16, j-permuted per 32-block
    const float* __restrict__ lam_p,
    unsigned short* __restrict__ o_ws)        // [B*L][1024] bf16
{
    constexpr int L = 2048, TD = 3072;

    // 64 KiB: [0,32768) = Ks[4][64][64], [32768,65536) = Vs[4][64][64].
    // After the loop's final barrier the space is reused as Red[4][2][4][64]
    // (f32x4, 32 KiB @0) + Lred[4][2][64] (2 KiB @32768).
    __shared__ __align__(16) unsigned char smem[65536];
    auto Ks = reinterpret_cast<unsigned short(*)[64][64]>(smem);
    auto Vs = reinterpret_cast<unsigned short(*)[64][64]>(smem + 32768);
    auto Red = reinterpret_cast<f32x4(*)[2][4][64]>(smem);
    auto Lred = reinterpret_cast<float(*)[2][64]>(smem + 32768);

    const int tid = threadIdx.x;
    const int wave = tid >> 6, lane = tid & 63;
    const int qw = wave & 3, jw = wave >> 2;
    const int quad = lane >> 4, ln = lane & 15;
    const int bh = blockIdx.y, b = bh >> 4, h = bh & 15;
    const int q0 = blockIdx.x * 128;
    const size_t seqbase = (size_t)b * L;
    const unsigned short* base = qkv + seqbase * TD + h * 64;
    const unsigned short* kb = base + 1024;
    const unsigned short* vbase = vdt + (size_t)bh * 64 * 2048;

    const int lsl = lane >> 3;
    const int cgl = (lane & 7) ^ lsl;

    const float lam = lam_p[0];
    asm volatile("" :: "v"(lam));

    // Q fragments (layout serves as MFMA B-operand: n=ln -> q, k=quad*8+u -> d)
    s16x8 qf[2][2];
#pragma unroll
    for (int s = 0; s < 2; ++s) {
        const unsigned short* qrow =
            base + (size_t)(q0 + qw * 32 + s * 16 + ln) * TD;
        qf[s][0] = *(const s16x8*)(qrow + quad * 8);
        qf[s][1] = *(const s16x8*)(qrow + 32 + quad * 8);
    }

    // each of 8 waves stages 8 rows of K and 8 rows of Vd^T (1 KiB each); 2 vmem ops
    auto stage = [&](int p, int j0) {
        const unsigned short* k0p = kb + (size_t)(j0 + wave * 8 + lsl) * TD + cgl * 8;
        gload16(k0p, &Ks[p][wave * 8][0]);
        const unsigned short* v0p = vbase + (size_t)(wave * 8 + lsl) * 2048 + j0 + cgl * 8;
        gload16(v0p, &Vs[p][wave * 8][0]);
    };

    f32x4 Ot[2][4];    // O^T accumulators: q=ln, d = mt*16 + quad*4 + rg
    f32x4 lacc[2];     // row-sum accumulators via ones-MFMA (all rg equal)
#pragma unroll
    for (int s = 0; s < 2; ++s) {
        lacc[s] = f32x4{0.f, 0.f, 0.f, 0.f};
#pragma unroll
        for (int mt = 0; mt < 4; ++mt) Ot[s][mt] = f32x4{0.f, 0.f, 0.f, 0.f};
    }

    const s16x8 ones8 = {(short)0x3F80, (short)0x3F80, (short)0x3F80, (short)0x3F80,
                         (short)0x3F80, (short)0x3F80, (short)0x3F80, (short)0x3F80};
    const int kx0 = (quad ^ (ln & 7)) << 3;
    const int kx1 = ((quad + 4) ^ (ln & 7)) << 3;
    const int vx  = (((jw * 4 + quad) ^ (ln & 7))) << 3;   // V chunk for this wave's j-half

    // prologue: pair 0 (tiles 0,1) staged and drained once
    stage(0, 0);
    stage(1, 64);
    asm volatile("s_waitcnt vmcnt(0)" ::: "memory");
    __builtin_amdgcn_s_barrier();
    asm volatile("" ::: "memory");

    for (int i = 0; i < 16; ++i) {
        const int pb = (i & 1) * 2;            // buffers holding tiles 2i, 2i+1

        // prefetch pair i+1 into the pair consumed during iteration i-1
        if (i + 1 < 16) {
            stage(pb ^ 2, (2 * i + 2) * 64);
            stage((pb ^ 2) + 1, (2 * i + 3) * 64);
        }

        // two independent tile-chains; compiler interleaves MFMA/VALU across them
#pragma unroll
        for (int u = 0; u < 2; ++u) {
            const int c = pb + u;

            // ---- S^T = K Q^T over this wave's j-half (t2 = jw*2 + t) ----
            f32x4 ST[2][2];
#pragma unroll
            for (int t = 0; t < 2; ++t) {
                const int t2 = jw * 2 + t;
                s16x8 k0 = *(const s16x8*)&Ks[c][t2 * 16 + ln][kx0];
                s16x8 k1 = *(const s16x8*)&Ks[c][t2 * 16 + ln][kx1];
#pragma unroll
                for (int s = 0; s < 2; ++s) {
                    f32x4 z = f32x4{0.f, 0.f, 0.f, 0.f};
                    z = __builtin_amdgcn_mfma_f32_16x16x32_bf16(k0, qf[s][0], z, 0, 0, 0);
                    z = __builtin_amdgcn_mfma_f32_16x16x32_bf16(k1, qf[s][1], z, 0, 0, 0);
                    ST[s][t] = z;
                }
            }

            // ---- P'^T = exp2(S^T) packed to bf16 in-register as K=32 B-frag ----
            s16x8 pf8[2];
#pragma unroll
            for (int s = 0; s < 2; ++s) {
                unsigned int w[4];
#pragma unroll
                for (int t = 0; t < 2; ++t) {
                    unsigned int b0 = __builtin_bit_cast(unsigned int,
                        __builtin_amdgcn_exp2f(ST[s][t][0]));
                    unsigned int b1 = __builtin_bit_cast(unsigned int,
                        __builtin_amdgcn_exp2f(ST[s][t][1]));
                    unsigned int b2 = __builtin_bit_cast(unsigned int,
                        __builtin_amdgcn_exp2f(ST[s][t][2]));
                    unsigned int b3 = __builtin_bit_cast(unsigned int,
                        __builtin_amdgcn_exp2f(ST[s][t][3]));
                    w[t * 2]     = (b0 >> 16) | (b1 & 0xFFFF0000u);
                    w[t * 2 + 1] = (b2 >> 16) | (b3 & 0xFFFF0000u);
                }
                pf8[s] = __builtin_bit_cast(s16x8, (u32x4){w[0], w[1], w[2], w[3]});
            }

            // ---- partial row sums via ones-MFMA (K=32) ----
#pragma unroll
            for (int s = 0; s < 2; ++s)
                lacc[s] = __builtin_amdgcn_mfma_f32_16x16x32_bf16(
                    ones8, pf8[s], lacc[s], 0, 0, 0);

            // ---- O^T += Vd'^T P'^T over this wave's j-half (K=32) ----
#pragma unroll
            for (int mt = 0; mt < 4; ++mt) {
                s16x8 vf = *(const s16x8*)&Vs[c][mt * 16 + ln][vx];
#pragma unroll
                for (int s = 0; s < 2; ++s)
                    Ot[s][mt] = __builtin_amdgcn_mfma_f32_16x16x32_bf16(
                        vf, pf8[s], Ot[s][mt], 0, 0, 0);
            }
        }

        // drain this iteration's prefetch (had a full 2-tile compute of cover)
        asm volatile("s_waitcnt vmcnt(0)" ::: "memory");
        __builtin_amdgcn_s_barrier();
        asm volatile("" ::: "memory");
    }

    // ---- cross-jw reduction through LDS (aliased), epilogue by jw==0 waves ----
    if (jw == 1) {
#pragma unroll
        for (int s = 0; s < 2; ++s) {
            Lred[qw][s][lane] = lacc[s][0];
#pragma unroll
            for (int mt = 0; mt < 4; ++mt) Red[qw][s][mt][lane] = Ot[s][mt];
        }
    }
    __syncthreads();
    if (jw == 0) {
#pragma unroll
        for (int s = 0; s < 2; ++s) {
            float lsum = lacc[s][0] + Lred[qw][s][lane];
            float inv = lam / lsum;
            int row = q0 + qw * 32 + s * 16 + ln;
            unsigned short* orow = o_ws + (seqbase + row) * 1024 + h * 64 + quad * 4;
#pragma unroll
            for (int mt = 0; mt < 4; ++mt) {
                f32x4 r = Red[qw][s][mt][lane];
                ushort4 u;
                u.x = f2bf((Ot[s][mt][0] + r[0]) * inv);
                u.y = f2bf((Ot[s][mt][1] + r[1]) * inv);
                u.z = f2bf((Ot[s][mt][2] + r[2]) * inv);
                u.w = f2bf((Ot[s][mt][3] + r[3]) * inv);
                *(ushort4*)(orow + mt * 16) = u;
            }
        }
    }
}

extern "C" void kernel_launch(void* const* d_in, const int* in_sizes, int n_in,
                              void* d_out, int out_size, void* d_ws, size_t ws_size,
                              hipStream_t stream) {
    const float* x     = (const float*)d_in[0];
    const float* w_qkv = (const float*)d_in[1];
    const float* b_qkv = (const float*)d_in[2];
    const float* w_out = (const float*)d_in[3];
    const float* b_out = (const float*)d_in[4];
    const float* lam   = (const float*)d_in[5];
    float* out = (float*)d_out;

    unsigned short* xb   = (unsigned short*)d_ws;
    unsigned short* wqb  = xb   + (size_t)4096 * 1024;
    unsigned short* wob  = wqb  + (size_t)3072 * 1024;
    unsigned short* qkvb = wob  + (size_t)1024 * 1024;
    unsigned short* ob   = qkvb + (size_t)4096 * 3072;
    unsigned short* vdt  = ob   + (size_t)4096 * 1024;

    cvt_all<<<8192, 256, 0, stream>>>(x, w_qkv, w_out, xb, wqb, wob);

    // qkv = x @ w_qkv^T + b_qkv; Q cols (n<1024) pre-scaled by log2(e)/32
    gemm_nt_mfma<1, 128><<<dim3(24, 32), 256, 0, stream>>>(
        xb, wqb, b_qkv, qkvb, 4096, 3072, 1024, 1024, 0.045084222f);

    vd_transpose<<<dim3(32, 32), 256, 0, stream>>>(qkvb, vdt);

    diff_attn_v9<<<dim3(16, 32), 512, 0, stream>>>(qkvb, vdt, lam, ob);

    gemm_nt_mfma<0, 64><<<dim3(16, 32), 256, 0, stream>>>(
        ob, wob, b_out, out, 4096, 1024, 1024, 0, 1.f);
}

// Round 5
// 184.523 us; speedup vs baseline: 1.0093x; 1.0093x over previous
//
#include <hip/hip_runtime.h>
#include <hip/hip_bf16.h>
#include <stdint.h>

// bf16 MFMA pipeline, v10. B=2, L=2048, D=1024, H=16, dh=64.
// a2 = softmax(s_prev) is a column permutation of a1 -> o = lam * A1 @ (v - roll(v,-1)).
// v10 = v8 schedule (per-tile counted vmcnt(2) + barrier, 2-ahead prefetch) with
// VALU-issue cuts: 4 LDS buffers + 4x static unroll (compile-time buffer index
// -> ds_read immediate offsets, no runtime LDS addressing), v_cvt_pk_bf16_f32
// for the P-pack (1 op per bf16 pair, RNE), s_setprio(1) around MFMA clusters,
// hoisted loop-invariant stage base pointers.

typedef __attribute__((ext_vector_type(8))) short s16x8;
typedef __attribute__((ext_vector_type(4))) short s16x4;
typedef __attribute__((ext_vector_type(4))) float f32x4;
typedef __attribute__((ext_vector_type(4))) unsigned int u32x4;

__device__ __forceinline__ float bf2f(unsigned short u) {
    union { unsigned int i; float f; } x; x.i = ((unsigned int)u) << 16; return x.f;
}
__device__ __forceinline__ unsigned short f2bf(float f) {
    union { float f; unsigned int i; } x; x.f = f;
    unsigned int r = x.i + 0x7FFFu + ((x.i >> 16) & 1u);   // RNE
    return (unsigned short)(r >> 16);
}

// v_cvt_pk_bf16_f32: dst.lo = bf16(lo), dst.hi = bf16(hi), RNE. No builtin on gfx950.
__device__ __forceinline__ unsigned int cvtpk(float lo, float hi) {
    unsigned int r;
    asm("v_cvt_pk_bf16_f32 %0, %1, %2" : "=v"(r) : "v"(lo), "v"(hi));
    return r;
}

// async global->LDS, 16B/lane; LDS dest = wave-uniform base + lane*16
__device__ __forceinline__ void gload16(const void* g, void* l) {
    auto gp = reinterpret_cast<const __attribute__((address_space(1))) unsigned int*>(
        reinterpret_cast<uintptr_t>(g));
    auto lp = reinterpret_cast<__attribute__((address_space(3))) unsigned int*>(
        reinterpret_cast<uintptr_t>(l));
    __builtin_amdgcn_global_load_lds(gp, lp, 16, 0, 0);
}

__global__ __launch_bounds__(256) void cvt_all(
    const float* __restrict__ x, const float* __restrict__ wq,
    const float* __restrict__ wo,
    unsigned short* __restrict__ xb, unsigned short* __restrict__ wqb,
    unsigned short* __restrict__ wob)
{
    int i4 = blockIdx.x * 256 + threadIdx.x;   // float4 index
    const float* src; unsigned short* dst; int off;
    if (i4 < 1048576)            { src = x;  dst = xb;  off = i4; }
    else if (i4 < 1048576 + 786432) { src = wq; dst = wqb; off = i4 - 1048576; }
    else                         { src = wo; dst = wob; off = i4 - 1835008; }
    float4 v = ((const float4*)src)[off];
    ushort4 u;
    u.x = f2bf(v.x); u.y = f2bf(v.y); u.z = f2bf(v.z); u.w = f2bf(v.w);
    ((ushort4*)dst)[off] = u;
}

// vdt[b][h][dh][pos] = v[b, j(pos), h, dh] - v[b, (j(pos)+1)%L, h, dh], transposed
// via LDS. Within each 32-j block, pos(j) = ((j>>2)&3)*8 + ((j>>4)&1)*4 + (j&3),
// i.e. position k = quad*8 + t*4 + rg holds j = t*16 + quad*4 + rg — the exact
// k-layout of the 16x16x32 MFMA A/B operand vs the 16x16 C-layout of S^T.
__global__ __launch_bounds__(256) void vd_transpose(
    const unsigned short* __restrict__ qkvb, unsigned short* __restrict__ vdt)
{
    __shared__ unsigned short T[64][72];
    const int tid = threadIdx.x;
    const int j0 = blockIdx.x * 64;
    const int bh = blockIdx.y, b = bh >> 4, h = bh & 15;
    const unsigned short* vb = qkvb + (size_t)b * 2048 * 3072 + 2048 + h * 64;

    int r = tid >> 2, cq = tid & 3;
    int rp = (r & 35) | ((r & 12) << 1) | ((r & 16) >> 2);   // permuted column
    int j = j0 + r, jn = (j + 1) & 2047;
    const unsigned short* p0 = vb + (size_t)j  * 3072 + cq * 16;
    const unsigned short* p1 = vb + (size_t)jn * 3072 + cq * 16;
    s16x8 a0 = *(const s16x8*)p0, a1 = *(const s16x8*)(p0 + 8);
    s16x8 b0 = *(const s16x8*)p1, b1 = *(const s16x8*)(p1 + 8);
#pragma unroll
    for (int u = 0; u < 8; ++u)
        T[cq * 16 + u][rp] = f2bf(bf2f((unsigned short)a0[u]) - bf2f((unsigned short)b0[u]));
#pragma unroll
    for (int u = 0; u < 8; ++u)
        T[cq * 16 + 8 + u][rp] = f2bf(bf2f((unsigned short)a1[u]) - bf2f((unsigned short)b1[u]));
    __syncthreads();

    int row = tid >> 2, sc = tid & 3;
    s16x8 o0 = *(const s16x8*)&T[row][sc * 16];
    s16x8 o1 = *(const s16x8*)&T[row][sc * 16 + 8];
    unsigned short* dst = vdt + ((size_t)bh * 64 + row) * 2048 + j0 + sc * 16;
    *(s16x8*)dst = o0;
    *(s16x8*)(dst + 8) = o1;
}

// C[m,n] = sum_k A[m,k]*Bm[n,k] + bias[n]; cols < nscale additionally *= smul.
template <int OUT_BF16, int BN>
__global__ __launch_bounds__(256) void gemm_nt_mfma(
    const unsigned short* __restrict__ A,
    const unsigned short* __restrict__ Bm,
    const float* __restrict__ bias,
    void* __restrict__ C,
    int M, int N, int K, int nscale, float smul)
{
    constexpr int NT = BN / 32;
    __shared__ unsigned short As[2][128][32];
    __shared__ unsigned short Bs[2][BN][32];

    const int tid = threadIdx.x;
    const int wave = tid >> 6, lane = tid & 63;
    const int quad = lane >> 4, ln = lane & 15;
    const int wm = (wave >> 1) * 64, wn = (wave & 1) * (NT * 16);
    const int m0 = blockIdx.y * 128, n0 = blockIdx.x * BN;
    const int rA = wave * 16 + (lane >> 2);
    const int gsl = lane & 3;

    f32x4 acc[4][NT];
#pragma unroll
    for (int mt = 0; mt < 4; ++mt)
#pragma unroll
        for (int nt = 0; nt < NT; ++nt) acc[mt][nt] = f32x4{0.f, 0.f, 0.f, 0.f};

    auto stage = [&](int p, int k0) {
#pragma unroll
        for (int q = 0; q < 2; ++q) {
            int row = q * 64 + rA;
            int kg = gsl ^ ((row >> 1) & 3);
            gload16(A + (size_t)(m0 + row) * K + k0 + kg * 8,
                    &As[p][q * 64 + wave * 16][0]);
            if (q * 64 < BN)
                gload16(Bm + (size_t)(n0 + row) * K + k0 + kg * 8,
                        &Bs[p][q * 64 + wave * 16][0]);
        }
    };

    stage(0, 0);
    __syncthreads();
    int p = 0;
    for (int k0 = 0; k0 < K; k0 += 32) {
        if (k0 + 32 < K) stage(p ^ 1, k0 + 32);
        s16x8 af[4], bfr[NT];
#pragma unroll
        for (int mt = 0; mt < 4; ++mt) {
            int rr = wm + mt * 16 + ln;
            af[mt] = *(const s16x8*)&As[p][rr][((quad ^ ((rr >> 1) & 3)) & 3) * 8];
        }
#pragma unroll
        for (int nt = 0; nt < NT; ++nt) {
            int rr = wn + nt * 16 + ln;
            bfr[nt] = *(const s16x8*)&Bs[p][rr][((quad ^ ((rr >> 1) & 3)) & 3) * 8];
        }
#pragma unroll
        for (int mt = 0; mt < 4; ++mt)
#pragma unroll
            for (int nt = 0; nt < NT; ++nt)
                acc[mt][nt] = __builtin_amdgcn_mfma_f32_16x16x32_bf16(
                    af[mt], bfr[nt], acc[mt][nt], 0, 0, 0);
        __syncthreads();
        p ^= 1;
    }

    float bb[NT];
#pragma unroll
    for (int nt = 0; nt < NT; ++nt) bb[nt] = bias[n0 + wn + nt * 16 + ln];
#pragma unroll
    for (int mt = 0; mt < 4; ++mt)
#pragma unroll
        for (int nt = 0; nt < NT; ++nt) {
            int col = n0 + wn + nt * 16 + ln;
            float sc = (col < nscale) ? smul : 1.f;
#pragma unroll
            for (int rg = 0; rg < 4; ++rg) {
                int row = m0 + wm + mt * 16 + quad * 4 + rg;
                float v = (acc[mt][nt][rg] + bb[nt]) * sc;
                if (OUT_BF16)
                    ((unsigned short*)C)[(size_t)row * N + col] = f2bf(v);
                else
                    ((float*)C)[(size_t)row * N + col] = v;
            }
        }
}

// Differential attention, v10: 8 waves (512 thr). wave = jw*4+qw.
// qw owns 32 q-rows; jw in {0,1} owns a 32-row j-half of each 64-row K/V chunk.
// 4 LDS buffers, 4x statically-unrolled kt loop, 2-ahead prefetch, per-tile
// s_waitcnt vmcnt(2) + s_barrier. cvt_pk P-pack, setprio MFMA clusters.
// Cross-jw Ot/lacc reduction aliased onto staging LDS after the loop.
__global__ __launch_bounds__(512) void diff_attn_v10(
    const unsigned short* __restrict__ qkv,   // [B*L][3072] bf16 (Q pre-scaled by log2e/32)
    const unsigned short* __restrict__ vdt,   // [B*H][64][2048] bf16, j-permuted per 32-block
    const float* __restrict__ lam_p,
    unsigned short* __restrict__ o_ws)        // [B*L][1024] bf16
{
    constexpr int L = 2048, TD = 3072;

    // 64 KiB: [0,32768) = Ks[4][64][64], [32768,65536) = Vs[4][64][64].
    // After the loop's full drain the space is reused as Red[4][2][4][64]
    // (f32x4, 32 KiB @0) + Lred[4][2][64] (2 KiB @32768).
    __shared__ __align__(16) unsigned char smem[65536];
    auto Ks = reinterpret_cast<unsigned short(*)[64][64]>(smem);
    auto Vs = reinterpret_cast<unsigned short(*)[64][64]>(smem + 32768);
    auto Red = reinterpret_cast<f32x4(*)[2][4][64]>(smem);
    auto Lred = reinterpret_cast<float(*)[2][64]>(smem + 32768);

    const int tid = threadIdx.x;
    const int wave = tid >> 6, lane = tid & 63;
    const int qw = wave & 3, jw = wave >> 2;
    const int quad = lane >> 4, ln = lane & 15;
    const int bh = blockIdx.y, b = bh >> 4, h = bh & 15;
    const int q0 = blockIdx.x * 128;
    const size_t seqbase = (size_t)b * L;
    const unsigned short* base = qkv + seqbase * TD + h * 64;
    const unsigned short* kb = base + 1024;
    const unsigned short* vbase = vdt + (size_t)bh * 64 * 2048;

    const int lsl = lane >> 3;
    const int cgl = (lane & 7) ^ lsl;

    // lam: load and force-retire before the loop so the loop's vmem queue holds
    // ONLY the staging loads (vmcnt accounting depends on this).
    const float lam = lam_p[0];
    asm volatile("" :: "v"(lam));

    // Q fragments (layout serves as MFMA B-operand: n=ln -> q, k=quad*8+u -> d)
    s16x8 qf[2][2];
#pragma unroll
    for (int s = 0; s < 2; ++s) {
        const unsigned short* qrow =
            base + (size_t)(q0 + qw * 32 + s * 16 + ln) * TD;
        qf[s][0] = *(const s16x8*)(qrow + quad * 8);
        qf[s][1] = *(const s16x8*)(qrow + 32 + quad * 8);
    }

    // loop-invariant per-lane stage base pointers (only + j0*stride varies)
    const unsigned short* kstage = kb + (size_t)(wave * 8 + lsl) * TD + cgl * 8;
    const unsigned short* vstage = vbase + (size_t)(wave * 8 + lsl) * 2048 + cgl * 8;

    f32x4 Ot[2][4];    // O^T accumulators: q=ln, d = mt*16 + quad*4 + rg
    f32x4 lacc[2];     // row-sum accumulators via ones-MFMA (all rg equal)
#pragma unroll
    for (int s = 0; s < 2; ++s) {
        lacc[s] = f32x4{0.f, 0.f, 0.f, 0.f};
#pragma unroll
        for (int mt = 0; mt < 4; ++mt) Ot[s][mt] = f32x4{0.f, 0.f, 0.f, 0.f};
    }

    const s16x8 ones8 = {(short)0x3F80, (short)0x3F80, (short)0x3F80, (short)0x3F80,
                         (short)0x3F80, (short)0x3F80, (short)0x3F80, (short)0x3F80};
    const int kx0 = (quad ^ (ln & 7)) << 3;
    const int kx1 = ((quad + 4) ^ (ln & 7)) << 3;
    const int vx  = (((jw * 4 + quad) ^ (ln & 7))) << 3;   // V chunk for this wave's j-half

    // one tile: compute buffer C (compile-time), stage buffer CS with seq chunk j0s
    auto body = [&](auto cc, auto ccs, int j0s) {
        constexpr int c  = decltype(cc)::value;
        constexpr int cs = decltype(ccs)::value;

        // stage tile (2 vmem ops) into the buffer consumed two tiles ago
        gload16(kstage + (size_t)j0s * TD, &Ks[cs][wave * 8][0]);
        gload16(vstage + j0s,              &Vs[cs][wave * 8][0]);

        // ---- S^T = K Q^T over this wave's j-half (t2 = jw*2 + t) ----
        // A = K-frag (m=j), B = qf (n=q). C: col=ln->q, row=quad*4+rg->j
        f32x4 ST[2][2];
        __builtin_amdgcn_s_setprio(1);
#pragma unroll
        for (int t = 0; t < 2; ++t) {
            const int t2 = jw * 2 + t;
            s16x8 k0 = *(const s16x8*)&Ks[c][t2 * 16 + ln][kx0];
            s16x8 k1 = *(const s16x8*)&Ks[c][t2 * 16 + ln][kx1];
#pragma unroll
            for (int s = 0; s < 2; ++s) {
                f32x4 z = f32x4{0.f, 0.f, 0.f, 0.f};
                z = __builtin_amdgcn_mfma_f32_16x16x32_bf16(k0, qf[s][0], z, 0, 0, 0);
                z = __builtin_amdgcn_mfma_f32_16x16x32_bf16(k1, qf[s][1], z, 0, 0, 0);
                ST[s][t] = z;
            }
        }
        __builtin_amdgcn_s_setprio(0);

        // ---- P'^T = exp2(S^T), cvt_pk to bf16 K=32 B-frag (RNE, 1 op/pair) ----
        // word t*2+w holds k-positions {quad*8 + t*4 + 2w, +1} = j {t*16+quad*4+2w, +1}
        s16x8 pf8[2];
#pragma unroll
        for (int s = 0; s < 2; ++s) {
            unsigned int w[4];
#pragma unroll
            for (int t = 0; t < 2; ++t) {
                float e0 = __builtin_amdgcn_exp2f(ST[s][t][0]);
                float e1 = __builtin_amdgcn_exp2f(ST[s][t][1]);
                float e2 = __builtin_amdgcn_exp2f(ST[s][t][2]);
                float e3 = __builtin_amdgcn_exp2f(ST[s][t][3]);
                w[t * 2]     = cvtpk(e0, e1);
                w[t * 2 + 1] = cvtpk(e2, e3);
            }
            pf8[s] = __builtin_bit_cast(s16x8, (u32x4){w[0], w[1], w[2], w[3]});
        }

        // ---- row sums (ones-MFMA) + O^T += Vd'^T P'^T, K=32 ----
        __builtin_amdgcn_s_setprio(1);
#pragma unroll
        for (int s = 0; s < 2; ++s)
            lacc[s] = __builtin_amdgcn_mfma_f32_16x16x32_bf16(
                ones8, pf8[s], lacc[s], 0, 0, 0);
#pragma unroll
        for (int mt = 0; mt < 4; ++mt) {
            s16x8 vf = *(const s16x8*)&Vs[c][mt * 16 + ln][vx];
#pragma unroll
            for (int s = 0; s < 2; ++s)
                Ot[s][mt] = __builtin_amdgcn_mfma_f32_16x16x32_bf16(
                    vf, pf8[s], Ot[s][mt], 0, 0, 0);
        }
        __builtin_amdgcn_s_setprio(0);

        // counted wait: this tile's stage (+ previous) stays in flight (2 ops);
        // the NEXT tile's buffer is complete after this.
        asm volatile("s_waitcnt vmcnt(2)" ::: "memory");
        __builtin_amdgcn_s_barrier();
        asm volatile("" ::: "memory");
    };

    // prologue: buffers 0 and 1 staged; wait buffer 0 (2 outstanding = buf1)
    gload16(kstage, &Ks[0][wave * 8][0]);
    gload16(vstage, &Vs[0][wave * 8][0]);
    gload16(kstage + (size_t)64 * TD, &Ks[1][wave * 8][0]);
    gload16(vstage + 64,              &Vs[1][wave * 8][0]);
    asm volatile("s_waitcnt vmcnt(2)" ::: "memory");
    __builtin_amdgcn_s_barrier();
    asm volatile("" ::: "memory");

    using I0 = std::integral_constant<int, 0>;
    using I1 = std::integral_constant<int, 1>;
    using I2 = std::integral_constant<int, 2>;
    using I3 = std::integral_constant<int, 3>;
    for (int it = 0; it < 8; ++it) {
        const int kt4 = it * 4;
        // tile kt uses buffer kt&3; stages tile kt+2 into buffer (kt+2)&3
        // (j0 wraps mod L near the end: discarded data, uniform vmcnt accounting)
        body(I0{}, I2{}, ((kt4 + 2) & 31) * 64);
        body(I1{}, I3{}, ((kt4 + 3) & 31) * 64);
        body(I2{}, I0{}, ((kt4 + 4) & 31) * 64);
        body(I3{}, I1{}, ((kt4 + 5) & 31) * 64);
    }

    // full drain (trailing wrap-stage loads) before aliasing LDS as Red/Lred
    __syncthreads();

    // ---- cross-jw reduction through LDS, then epilogue by jw==0 waves ----
    if (jw == 1) {
#pragma unroll
        for (int s = 0; s < 2; ++s) {
            Lred[qw][s][lane] = lacc[s][0];
#pragma unroll
            for (int mt = 0; mt < 4; ++mt) Red[qw][s][mt][lane] = Ot[s][mt];
        }
    }
    __syncthreads();
    if (jw == 0) {
#pragma unroll
        for (int s = 0; s < 2; ++s) {
            float lsum = lacc[s][0] + Lred[qw][s][lane];
            float inv = lam / lsum;
            int row = q0 + qw * 32 + s * 16 + ln;
            unsigned short* orow = o_ws + (seqbase + row) * 1024 + h * 64 + quad * 4;
#pragma unroll
            for (int mt = 0; mt < 4; ++mt) {
                f32x4 r = Red[qw][s][mt][lane];
                ushort4 u;
                u.x = f2bf((Ot[s][mt][0] + r[0]) * inv);
                u.y = f2bf((Ot[s][mt][1] + r[1]) * inv);
                u.z = f2bf((Ot[s][mt][2] + r[2]) * inv);
                u.w = f2bf((Ot[s][mt][3] + r[3]) * inv);
                *(ushort4*)(orow + mt * 16) = u;
            }
        }
    }
}

extern "C" void kernel_launch(void* const* d_in, const int* in_sizes, int n_in,
                              void* d_out, int out_size, void* d_ws, size_t ws_size,
                              hipStream_t stream) {
    const float* x     = (const float*)d_in[0];
    const float* w_qkv = (const float*)d_in[1];
    const float* b_qkv = (const float*)d_in[2];
    const float* w_out = (const float*)d_in[3];
    const float* b_out = (const float*)d_in[4];
    const float* lam   = (const float*)d_in[5];
    float* out = (float*)d_out;

    unsigned short* xb   = (unsigned short*)d_ws;
    unsigned short* wqb  = xb   + (size_t)4096 * 1024;
    unsigned short* wob  = wqb  + (size_t)3072 * 1024;
    unsigned short* qkvb = wob  + (size_t)1024 * 1024;
    unsigned short* ob   = qkvb + (size_t)4096 * 3072;
    unsigned short* vdt  = ob   + (size_t)4096 * 1024;

    cvt_all<<<8192, 256, 0, stream>>>(x, w_qkv, w_out, xb, wqb, wob);

    // qkv = x @ w_qkv^T + b_qkv; Q cols (n<1024) pre-scaled by log2(e)/32
    gemm_nt_mfma<1, 128><<<dim3(24, 32), 256, 0, stream>>>(
        xb, wqb, b_qkv, qkvb, 4096, 3072, 1024, 1024, 0.045084222f);

    vd_transpose<<<dim3(32, 32), 256, 0, stream>>>(qkvb, vdt);

    diff_attn_v10<<<dim3(16, 32), 512, 0, stream>>>(qkvb, vdt, lam, ob);

    gemm_nt_mfma<0, 64><<<dim3(16, 32), 256, 0, stream>>>(
        ob, wob, b_out, out, 4096, 1024, 1024, 0, 1.f);
}

// Round 6
// 179.868 us; speedup vs baseline: 1.0355x; 1.0259x over previous
//
#include <hip/hip_runtime.h>
#include <hip/hip_bf16.h>
#include <stdint.h>

// bf16 MFMA pipeline, v11. B=2, L=2048, D=1024, H=16, dh=64.
// a2 = softmax(s_prev) is a column permutation of a1 -> o = lam * A1 @ (v - roll(v,-1)).
// v11: gemm_nt_mfma gets the attn-v8 deep pipeline (proven -11% there): 3 LDS
// buffers, stage issued 2 K-tiles ahead, per-iter s_waitcnt vmcnt(LPS) + raw
// s_barrier (never drain to 0 in the loop). Tail stages clamp to the last tile
// (L2-hot). Attention = v10 (unchanged).

typedef __attribute__((ext_vector_type(8))) short s16x8;
typedef __attribute__((ext_vector_type(4))) short s16x4;
typedef __attribute__((ext_vector_type(4))) float f32x4;
typedef __attribute__((ext_vector_type(4))) unsigned int u32x4;

__device__ __forceinline__ float bf2f(unsigned short u) {
    union { unsigned int i; float f; } x; x.i = ((unsigned int)u) << 16; return x.f;
}
__device__ __forceinline__ unsigned short f2bf(float f) {
    union { float f; unsigned int i; } x; x.f = f;
    unsigned int r = x.i + 0x7FFFu + ((x.i >> 16) & 1u);   // RNE
    return (unsigned short)(r >> 16);
}

// v_cvt_pk_bf16_f32: dst.lo = bf16(lo), dst.hi = bf16(hi), RNE. No builtin on gfx950.
__device__ __forceinline__ unsigned int cvtpk(float lo, float hi) {
    unsigned int r;
    asm("v_cvt_pk_bf16_f32 %0, %1, %2" : "=v"(r) : "v"(lo), "v"(hi));
    return r;
}

// async global->LDS, 16B/lane; LDS dest = wave-uniform base + lane*16
__device__ __forceinline__ void gload16(const void* g, void* l) {
    auto gp = reinterpret_cast<const __attribute__((address_space(1))) unsigned int*>(
        reinterpret_cast<uintptr_t>(g));
    auto lp = reinterpret_cast<__attribute__((address_space(3))) unsigned int*>(
        reinterpret_cast<uintptr_t>(l));
    __builtin_amdgcn_global_load_lds(gp, lp, 16, 0, 0);
}

__global__ __launch_bounds__(256) void cvt_all(
    const float* __restrict__ x, const float* __restrict__ wq,
    const float* __restrict__ wo,
    unsigned short* __restrict__ xb, unsigned short* __restrict__ wqb,
    unsigned short* __restrict__ wob)
{
    int i4 = blockIdx.x * 256 + threadIdx.x;   // float4 index
    const float* src; unsigned short* dst; int off;
    if (i4 < 1048576)            { src = x;  dst = xb;  off = i4; }
    else if (i4 < 1048576 + 786432) { src = wq; dst = wqb; off = i4 - 1048576; }
    else                         { src = wo; dst = wob; off = i4 - 1835008; }
    float4 v = ((const float4*)src)[off];
    ushort4 u;
    u.x = f2bf(v.x); u.y = f2bf(v.y); u.z = f2bf(v.z); u.w = f2bf(v.w);
    ((ushort4*)dst)[off] = u;
}

// vdt[b][h][dh][pos] = v[b, j(pos), h, dh] - v[b, (j(pos)+1)%L, h, dh], transposed
// via LDS. Within each 32-j block, pos(j) = ((j>>2)&3)*8 + ((j>>4)&1)*4 + (j&3),
// i.e. position k = quad*8 + t*4 + rg holds j = t*16 + quad*4 + rg — the exact
// k-layout of the 16x16x32 MFMA A/B operand vs the 16x16 C-layout of S^T.
__global__ __launch_bounds__(256) void vd_transpose(
    const unsigned short* __restrict__ qkvb, unsigned short* __restrict__ vdt)
{
    __shared__ unsigned short T[64][72];
    const int tid = threadIdx.x;
    const int j0 = blockIdx.x * 64;
    const int bh = blockIdx.y, b = bh >> 4, h = bh & 15;
    const unsigned short* vb = qkvb + (size_t)b * 2048 * 3072 + 2048 + h * 64;

    int r = tid >> 2, cq = tid & 3;
    int rp = (r & 35) | ((r & 12) << 1) | ((r & 16) >> 2);   // permuted column
    int j = j0 + r, jn = (j + 1) & 2047;
    const unsigned short* p0 = vb + (size_t)j  * 3072 + cq * 16;
    const unsigned short* p1 = vb + (size_t)jn * 3072 + cq * 16;
    s16x8 a0 = *(const s16x8*)p0, a1 = *(const s16x8*)(p0 + 8);
    s16x8 b0 = *(const s16x8*)p1, b1 = *(const s16x8*)(p1 + 8);
#pragma unroll
    for (int u = 0; u < 8; ++u)
        T[cq * 16 + u][rp] = f2bf(bf2f((unsigned short)a0[u]) - bf2f((unsigned short)b0[u]));
#pragma unroll
    for (int u = 0; u < 8; ++u)
        T[cq * 16 + 8 + u][rp] = f2bf(bf2f((unsigned short)a1[u]) - bf2f((unsigned short)b1[u]));
    __syncthreads();

    int row = tid >> 2, sc = tid & 3;
    s16x8 o0 = *(const s16x8*)&T[row][sc * 16];
    s16x8 o1 = *(const s16x8*)&T[row][sc * 16 + 8];
    unsigned short* dst = vdt + ((size_t)bh * 64 + row) * 2048 + j0 + sc * 16;
    *(s16x8*)dst = o0;
    *(s16x8*)(dst + 8) = o1;
}

// C[m,n] = sum_k A[m,k]*Bm[n,k] + bias[n]; cols < nscale additionally *= smul.
// v11: 3-buffer deep pipeline, 2-ahead stage, counted vmcnt + raw s_barrier.
template <int OUT_BF16, int BN>
__global__ __launch_bounds__(256) void gemm_nt_mfma(
    const unsigned short* __restrict__ A,
    const unsigned short* __restrict__ Bm,
    const float* __restrict__ bias,
    void* __restrict__ C,
    int M, int N, int K, int nscale, float smul)
{
    constexpr int NT = BN / 32;
    constexpr int LPS = 2 + BN / 64;        // gload16 per wave per stage
    __shared__ unsigned short As[3][128][32];
    __shared__ unsigned short Bs[3][BN][32];

    const int tid = threadIdx.x;
    const int wave = tid >> 6, lane = tid & 63;
    const int quad = lane >> 4, ln = lane & 15;
    const int wm = (wave >> 1) * 64, wn = (wave & 1) * (NT * 16);
    const int m0 = blockIdx.y * 128, n0 = blockIdx.x * BN;
    const int rA = wave * 16 + (lane >> 2);
    const int gsl = lane & 3;

    f32x4 acc[4][NT];
#pragma unroll
    for (int mt = 0; mt < 4; ++mt)
#pragma unroll
        for (int nt = 0; nt < NT; ++nt) acc[mt][nt] = f32x4{0.f, 0.f, 0.f, 0.f};

    auto stage = [&](int p, int k0) {
#pragma unroll
        for (int q = 0; q < 2; ++q) {
            int row = q * 64 + rA;
            int kg = gsl ^ ((row >> 1) & 3);
            gload16(A + (size_t)(m0 + row) * K + k0 + kg * 8,
                    &As[p][q * 64 + wave * 16][0]);
            if (q * 64 < BN)
                gload16(Bm + (size_t)(n0 + row) * K + k0 + kg * 8,
                        &Bs[p][q * 64 + wave * 16][0]);
        }
    };

    auto wait_lps = [&]() {
        if constexpr (LPS == 4) asm volatile("s_waitcnt vmcnt(4)" ::: "memory");
        else                    asm volatile("s_waitcnt vmcnt(3)" ::: "memory");
    };

    // prologue: tiles 0 and 1 in flight; wait tile 0 (LPS outstanding = tile 1)
    stage(0, 0);
    stage(1, 32);
    wait_lps();
    __builtin_amdgcn_s_barrier();
    asm volatile("" ::: "memory");

    int p = 0;
    for (int k0 = 0; k0 < K; k0 += 32) {
        // stage tile k+2 into the buffer consumed last iteration (p-1 mod 3).
        // Tail: clamp to last tile (L2-hot refetch, uniform vmcnt accounting).
        int p2 = p + 2; if (p2 >= 3) p2 -= 3;
        int ks = k0 + 64; if (ks >= K) ks = K - 32;
        stage(p2, ks);

        s16x8 af[4], bfr[NT];
#pragma unroll
        for (int mt = 0; mt < 4; ++mt) {
            int rr = wm + mt * 16 + ln;
            af[mt] = *(const s16x8*)&As[p][rr][((quad ^ ((rr >> 1) & 3)) & 3) * 8];
        }
#pragma unroll
        for (int nt = 0; nt < NT; ++nt) {
            int rr = wn + nt * 16 + ln;
            bfr[nt] = *(const s16x8*)&Bs[p][rr][((quad ^ ((rr >> 1) & 3)) & 3) * 8];
        }
#pragma unroll
        for (int mt = 0; mt < 4; ++mt)
#pragma unroll
            for (int nt = 0; nt < NT; ++nt)
                acc[mt][nt] = __builtin_amdgcn_mfma_f32_16x16x32_bf16(
                    af[mt], bfr[nt], acc[mt][nt], 0, 0, 0);

        // counted wait: tile k+2's LPS loads stay in flight; tile k+1 complete.
        wait_lps();
        __builtin_amdgcn_s_barrier();
        asm volatile("" ::: "memory");
        p = (p == 2) ? 0 : p + 1;
    }

    float bb[NT];
#pragma unroll
    for (int nt = 0; nt < NT; ++nt) bb[nt] = bias[n0 + wn + nt * 16 + ln];
#pragma unroll
    for (int mt = 0; mt < 4; ++mt)
#pragma unroll
        for (int nt = 0; nt < NT; ++nt) {
            int col = n0 + wn + nt * 16 + ln;
            float sc = (col < nscale) ? smul : 1.f;
#pragma unroll
            for (int rg = 0; rg < 4; ++rg) {
                int row = m0 + wm + mt * 16 + quad * 4 + rg;
                float v = (acc[mt][nt][rg] + bb[nt]) * sc;
                if (OUT_BF16)
                    ((unsigned short*)C)[(size_t)row * N + col] = f2bf(v);
                else
                    ((float*)C)[(size_t)row * N + col] = v;
            }
        }
}

// Differential attention, v10 (unchanged): 8 waves (512 thr). wave = jw*4+qw.
// qw owns 32 q-rows; jw in {0,1} owns a 32-row j-half of each 64-row K/V chunk.
// 4 LDS buffers, 4x statically-unrolled kt loop, 2-ahead prefetch, per-tile
// s_waitcnt vmcnt(2) + s_barrier. cvt_pk P-pack, setprio MFMA clusters.
// Cross-jw Ot/lacc reduction aliased onto staging LDS after the loop.
__global__ __launch_bounds__(512) void diff_attn_v10(
    const unsigned short* __restrict__ qkv,   // [B*L][3072] bf16 (Q pre-scaled by log2e/32)
    const unsigned short* __restrict__ vdt,   // [B*H][64][2048] bf16, j-permuted per 32-block
    const float* __restrict__ lam_p,
    unsigned short* __restrict__ o_ws)        // [B*L][1024] bf16
{
    constexpr int L = 2048, TD = 3072;

    __shared__ __align__(16) unsigned char smem[65536];
    auto Ks = reinterpret_cast<unsigned short(*)[64][64]>(smem);
    auto Vs = reinterpret_cast<unsigned short(*)[64][64]>(smem + 32768);
    auto Red = reinterpret_cast<f32x4(*)[2][4][64]>(smem);
    auto Lred = reinterpret_cast<float(*)[2][64]>(smem + 32768);

    const int tid = threadIdx.x;
    const int wave = tid >> 6, lane = tid & 63;
    const int qw = wave & 3, jw = wave >> 2;
    const int quad = lane >> 4, ln = lane & 15;
    const int bh = blockIdx.y, b = bh >> 4, h = bh & 15;
    const int q0 = blockIdx.x * 128;
    const size_t seqbase = (size_t)b * L;
    const unsigned short* base = qkv + seqbase * TD + h * 64;
    const unsigned short* kb = base + 1024;
    const unsigned short* vbase = vdt + (size_t)bh * 64 * 2048;

    const int lsl = lane >> 3;
    const int cgl = (lane & 7) ^ lsl;

    const float lam = lam_p[0];
    asm volatile("" :: "v"(lam));

    s16x8 qf[2][2];
#pragma unroll
    for (int s = 0; s < 2; ++s) {
        const unsigned short* qrow =
            base + (size_t)(q0 + qw * 32 + s * 16 + ln) * TD;
        qf[s][0] = *(const s16x8*)(qrow + quad * 8);
        qf[s][1] = *(const s16x8*)(qrow + 32 + quad * 8);
    }

    const unsigned short* kstage = kb + (size_t)(wave * 8 + lsl) * TD + cgl * 8;
    const unsigned short* vstage = vbase + (size_t)(wave * 8 + lsl) * 2048 + cgl * 8;

    f32x4 Ot[2][4];
    f32x4 lacc[2];
#pragma unroll
    for (int s = 0; s < 2; ++s) {
        lacc[s] = f32x4{0.f, 0.f, 0.f, 0.f};
#pragma unroll
        for (int mt = 0; mt < 4; ++mt) Ot[s][mt] = f32x4{0.f, 0.f, 0.f, 0.f};
    }

    const s16x8 ones8 = {(short)0x3F80, (short)0x3F80, (short)0x3F80, (short)0x3F80,
                         (short)0x3F80, (short)0x3F80, (short)0x3F80, (short)0x3F80};
    const int kx0 = (quad ^ (ln & 7)) << 3;
    const int kx1 = ((quad + 4) ^ (ln & 7)) << 3;
    const int vx  = (((jw * 4 + quad) ^ (ln & 7))) << 3;

    auto body = [&](auto cc, auto ccs, int j0s) {
        constexpr int c  = decltype(cc)::value;
        constexpr int cs = decltype(ccs)::value;

        gload16(kstage + (size_t)j0s * TD, &Ks[cs][wave * 8][0]);
        gload16(vstage + j0s,              &Vs[cs][wave * 8][0]);

        f32x4 ST[2][2];
        __builtin_amdgcn_s_setprio(1);
#pragma unroll
        for (int t = 0; t < 2; ++t) {
            const int t2 = jw * 2 + t;
            s16x8 k0 = *(const s16x8*)&Ks[c][t2 * 16 + ln][kx0];
            s16x8 k1 = *(const s16x8*)&Ks[c][t2 * 16 + ln][kx1];
#pragma unroll
            for (int s = 0; s < 2; ++s) {
                f32x4 z = f32x4{0.f, 0.f, 0.f, 0.f};
                z = __builtin_amdgcn_mfma_f32_16x16x32_bf16(k0, qf[s][0], z, 0, 0, 0);
                z = __builtin_amdgcn_mfma_f32_16x16x32_bf16(k1, qf[s][1], z, 0, 0, 0);
                ST[s][t] = z;
            }
        }
        __builtin_amdgcn_s_setprio(0);

        s16x8 pf8[2];
#pragma unroll
        for (int s = 0; s < 2; ++s) {
            unsigned int w[4];
#pragma unroll
            for (int t = 0; t < 2; ++t) {
                float e0 = __builtin_amdgcn_exp2f(ST[s][t][0]);
                float e1 = __builtin_amdgcn_exp2f(ST[s][t][1]);
                float e2 = __builtin_amdgcn_exp2f(ST[s][t][2]);
                float e3 = __builtin_amdgcn_exp2f(ST[s][t][3]);
                w[t * 2]     = cvtpk(e0, e1);
                w[t * 2 + 1] = cvtpk(e2, e3);
            }
            pf8[s] = __builtin_bit_cast(s16x8, (u32x4){w[0], w[1], w[2], w[3]});
        }

        __builtin_amdgcn_s_setprio(1);
#pragma unroll
        for (int s = 0; s < 2; ++s)
            lacc[s] = __builtin_amdgcn_mfma_f32_16x16x32_bf16(
                ones8, pf8[s], lacc[s], 0, 0, 0);
#pragma unroll
        for (int mt = 0; mt < 4; ++mt) {
            s16x8 vf = *(const s16x8*)&Vs[c][mt * 16 + ln][vx];
#pragma unroll
            for (int s = 0; s < 2; ++s)
                Ot[s][mt] = __builtin_amdgcn_mfma_f32_16x16x32_bf16(
                    vf, pf8[s], Ot[s][mt], 0, 0, 0);
        }
        __builtin_amdgcn_s_setprio(0);

        asm volatile("s_waitcnt vmcnt(2)" ::: "memory");
        __builtin_amdgcn_s_barrier();
        asm volatile("" ::: "memory");
    };

    gload16(kstage, &Ks[0][wave * 8][0]);
    gload16(vstage, &Vs[0][wave * 8][0]);
    gload16(kstage + (size_t)64 * TD, &Ks[1][wave * 8][0]);
    gload16(vstage + 64,              &Vs[1][wave * 8][0]);
    asm volatile("s_waitcnt vmcnt(2)" ::: "memory");
    __builtin_amdgcn_s_barrier();
    asm volatile("" ::: "memory");

    using I0 = std::integral_constant<int, 0>;
    using I1 = std::integral_constant<int, 1>;
    using I2 = std::integral_constant<int, 2>;
    using I3 = std::integral_constant<int, 3>;
    for (int it = 0; it < 8; ++it) {
        const int kt4 = it * 4;
        body(I0{}, I2{}, ((kt4 + 2) & 31) * 64);
        body(I1{}, I3{}, ((kt4 + 3) & 31) * 64);
        body(I2{}, I0{}, ((kt4 + 4) & 31) * 64);
        body(I3{}, I1{}, ((kt4 + 5) & 31) * 64);
    }

    __syncthreads();

    if (jw == 1) {
#pragma unroll
        for (int s = 0; s < 2; ++s) {
            Lred[qw][s][lane] = lacc[s][0];
#pragma unroll
            for (int mt = 0; mt < 4; ++mt) Red[qw][s][mt][lane] = Ot[s][mt];
        }
    }
    __syncthreads();
    if (jw == 0) {
#pragma unroll
        for (int s = 0; s < 2; ++s) {
            float lsum = lacc[s][0] + Lred[qw][s][lane];
            float inv = lam / lsum;
            int row = q0 + qw * 32 + s * 16 + ln;
            unsigned short* orow = o_ws + (seqbase + row) * 1024 + h * 64 + quad * 4;
#pragma unroll
            for (int mt = 0; mt < 4; ++mt) {
                f32x4 r = Red[qw][s][mt][lane];
                ushort4 u;
                u.x = f2bf((Ot[s][mt][0] + r[0]) * inv);
                u.y = f2bf((Ot[s][mt][1] + r[1]) * inv);
                u.z = f2bf((Ot[s][mt][2] + r[2]) * inv);
                u.w = f2bf((Ot[s][mt][3] + r[3]) * inv);
                *(ushort4*)(orow + mt * 16) = u;
            }
        }
    }
}

extern "C" void kernel_launch(void* const* d_in, const int* in_sizes, int n_in,
                              void* d_out, int out_size, void* d_ws, size_t ws_size,
                              hipStream_t stream) {
    const float* x     = (const float*)d_in[0];
    const float* w_qkv = (const float*)d_in[1];
    const float* b_qkv = (const float*)d_in[2];
    const float* w_out = (const float*)d_in[3];
    const float* b_out = (const float*)d_in[4];
    const float* lam   = (const float*)d_in[5];
    float* out = (float*)d_out;

    unsigned short* xb   = (unsigned short*)d_ws;
    unsigned short* wqb  = xb   + (size_t)4096 * 1024;
    unsigned short* wob  = wqb  + (size_t)3072 * 1024;
    unsigned short* qkvb = wob  + (size_t)1024 * 1024;
    unsigned short* ob   = qkvb + (size_t)4096 * 3072;
    unsigned short* vdt  = ob   + (size_t)4096 * 1024;

    cvt_all<<<8192, 256, 0, stream>>>(x, w_qkv, w_out, xb, wqb, wob);

    // qkv = x @ w_qkv^T + b_qkv; Q cols (n<1024) pre-scaled by log2(e)/32
    gemm_nt_mfma<1, 128><<<dim3(24, 32), 256, 0, stream>>>(
        xb, wqb, b_qkv, qkvb, 4096, 3072, 1024, 1024, 0.045084222f);

    vd_transpose<<<dim3(32, 32), 256, 0, stream>>>(qkvb, vdt);

    diff_attn_v10<<<dim3(16, 32), 512, 0, stream>>>(qkvb, vdt, lam, ob);

    gemm_nt_mfma<0, 64><<<dim3(16, 32), 256, 0, stream>>>(
        ob, wob, b_out, out, 4096, 1024, 1024, 0, 1.f);
}